// Round 7
// baseline (457.909 us; speedup 1.0000x reference)
//
#include <hip/hip_runtime.h>

// B=4 T=4096 D=1024 H=16 HD=64 K=32 ; inputs f32, OUTPUTS f32.
// NO d_ws usage: all scratch lives inside the 67.1 MB f32 output-0 region.
#define B_ 4
#define T_ 4096
#define D_ 1024
#define H_ 16
#define K_ 32

// ---------------------------------------------------------------------------
// Scratch layout (f32 indices into outF; out0 = floats [0, 16777216)):
//   xs    [0      ,131072)   B*K x 1024   [atomic]
//   xbar  [131072 ,135168)   B x 1024     [atomic]
//   pad   [135168 ,196608)   zeros (rows 132..191 of gemm#1 A)
//   qkv   [196608 ,786432)   192 x 3072   [atomic]
//   u     [786432 ,917504)   128 x 1024   [pure write]
//   Mm    [917504 ,1048576)  128 x 1024   [atomic]  = out0 t-rows [896,1024)
//   pulse outF[16777216 +64), resp outF[16777280 +2048)
// k4 phase A writes every out0 row EXCEPT [896,1024) (M's home);
// k4_tail (ONE block) preloads M[b=0] into LDS then overwrites [896,1024).
// ---------------------------------------------------------------------------

__global__ __launch_bounds__(256) void k0_init(float4* __restrict__ a, int na,
                                               float4* __restrict__ b, int nb)
{
  int i = blockIdx.x * 256 + threadIdx.x;
  float4 z; z.x = 0.f; z.y = 0.f; z.z = 0.f; z.w = 0.f;
  if (i < na) a[i] = z;
  if (i < nb) b[i] = z;
}

// ---------------------------------------------------------------------------
// K1: xs[b][k][c] += sum_t sb[b,t,k]*x[b,t,c];  xbar[b][c] += sum_t x[b,t,c]
// grid (2, B, 32), block 256; thread owns 2 consecutive c; t-chunk = 128.
// ---------------------------------------------------------------------------
__global__ __launch_bounds__(256) void k1_spectral(
    const float* __restrict__ x, const float* __restrict__ sb,
    float* __restrict__ xs, float* __restrict__ xbar)
{
  const int b  = blockIdx.y;
  const int t0 = blockIdx.z * 128;
  const int c0 = blockIdx.x * 512 + threadIdx.x * 2;
  __shared__ float sbs[128][33];
  #pragma unroll
  for (int i = 0; i < 16; i++){
    int idx = threadIdx.x + i * 256;           // 4096 = 128t * 32k
    int k = idx & 31, t = idx >> 5;
    sbs[t][k] = sb[(size_t)(b * T_ + t0 + t) * K_ + k];
  }
  __syncthreads();
  float accx[32], accy[32];
  #pragma unroll
  for (int k = 0; k < 32; k++){ accx[k] = 0.f; accy[k] = 0.f; }
  float amx = 0.f, amy = 0.f;
  const float* xp = x + (size_t)(b * T_ + t0) * D_ + c0;
  for (int t = 0; t < 128; ++t){
    float2 xv = *(const float2*)(xp + (size_t)t * D_);
    amx += xv.x; amy += xv.y;
    #pragma unroll
    for (int k = 0; k < 32; k++){
      float s = sbs[t][k];
      accx[k] = fmaf(s, xv.x, accx[k]);
      accy[k] = fmaf(s, xv.y, accy[k]);
    }
  }
  float* xsp = xs + (size_t)b * K_ * D_ + c0;
  #pragma unroll
  for (int k = 0; k < 32; k++){
    atomicAdd(xsp + (size_t)k * D_,     accx[k]);
    atomicAdd(xsp + (size_t)k * D_ + 1, accy[k]);
  }
  atomicAdd(xbar + b * D_ + c0,     amx);
  atomicAdd(xbar + b * D_ + c0 + 1, amy);
}

// ---------------------------------------------------------------------------
// gemm_aw: C[m][n] += sum_c A[m][c]*W[n][c];  A f32 scratch, W f32 input
// grid (N/64, M/64, csplit), block 256; 64x64 tile; LDS staged transposed.
// ---------------------------------------------------------------------------
__global__ __launch_bounds__(256) void gemm_aw(
    const float* __restrict__ A, const float* __restrict__ W,
    float* __restrict__ C, const int N, const int cPerSplit)
{
  __shared__ __align__(16) float As[64][68];
  __shared__ __align__(16) float Ws[64][68];
  const int nt = blockIdx.x, mt = blockIdx.y;
  const int cbase = blockIdx.z * cPerSplit;
  const int tx = threadIdx.x & 15, ty = threadIdx.x >> 4;
  float acc[4][4];
  #pragma unroll
  for (int i = 0; i < 4; i++)
    #pragma unroll
    for (int j = 0; j < 4; j++) acc[i][j] = 0.f;

  for (int cc = 0; cc < cPerSplit; cc += 64){
    const int cb = cbase + cc;
    if (cc) __syncthreads();
    #pragma unroll
    for (int i = 0; i < 16; i++){
      int idx = threadIdx.x + i * 256;          // 4096 = 64m * 64c
      int c = idx & 63, m = idx >> 6;
      As[c][m] = A[(size_t)(mt * 64 + m) * 1024 + cb + c];
    }
    #pragma unroll
    for (int i = 0; i < 16; i++){
      int idx = threadIdx.x + i * 256;          // 4096 = 64n * 64c
      int c = idx & 63, n = idx >> 6;
      Ws[c][n] = W[(size_t)(nt * 64 + n) * 1024 + cb + c];
    }
    __syncthreads();
    #pragma unroll 4
    for (int c = 0; c < 64; ++c){
      const float4 a4 = *(const float4*)&As[c][ty * 4];
      const float4 w4 = *(const float4*)&Ws[c][tx * 4];
      acc[0][0] = fmaf(a4.x, w4.x, acc[0][0]);
      acc[0][1] = fmaf(a4.x, w4.y, acc[0][1]);
      acc[0][2] = fmaf(a4.x, w4.z, acc[0][2]);
      acc[0][3] = fmaf(a4.x, w4.w, acc[0][3]);
      acc[1][0] = fmaf(a4.y, w4.x, acc[1][0]);
      acc[1][1] = fmaf(a4.y, w4.y, acc[1][1]);
      acc[1][2] = fmaf(a4.y, w4.z, acc[1][2]);
      acc[1][3] = fmaf(a4.y, w4.w, acc[1][3]);
      acc[2][0] = fmaf(a4.z, w4.x, acc[2][0]);
      acc[2][1] = fmaf(a4.z, w4.y, acc[2][1]);
      acc[2][2] = fmaf(a4.z, w4.z, acc[2][2]);
      acc[2][3] = fmaf(a4.z, w4.w, acc[2][3]);
      acc[3][0] = fmaf(a4.w, w4.x, acc[3][0]);
      acc[3][1] = fmaf(a4.w, w4.y, acc[3][1]);
      acc[3][2] = fmaf(a4.w, w4.z, acc[3][2]);
      acc[3][3] = fmaf(a4.w, w4.w, acc[3][3]);
    }
  }
  #pragma unroll
  for (int i = 0; i < 4; i++){
    float* crow = C + (size_t)(mt * 64 + ty * 4 + i) * N + nt * 64 + tx * 4;
    #pragma unroll
    for (int j = 0; j < 4; j++) atomicAdd(crow + j, acc[i][j]);
  }
}

// ---------------------------------------------------------------------------
// K3: pulse (qkv row 128+b = xbar@Wqkv.T), attn_spec, soliton ODE, u=resp*v_spec
// grid 64 blocks (b*16+h), 64 threads. All outputs f32.
// ---------------------------------------------------------------------------
__global__ __launch_bounds__(64) void k3_small(
    const float* __restrict__ qkvC,
    const float* __restrict__ W1, const float* __restrict__ b1,
    const float* __restrict__ W2, const float* __restrict__ b2,
    const float* __restrict__ filt,
    const float* __restrict__ a_in, const float* __restrict__ b_in,
    float* __restrict__ u, float* __restrict__ out_pulse,
    float* __restrict__ out_resp)
{
  const int b = blockIdx.x >> 4, h = blockIdx.x & 15;
  const int d = threadIdx.x;
  __shared__ float qm[64];
  __shared__ float h1s[32];
  __shared__ float rsp[32];
  qm[d] = qkvC[(size_t)(128 + b) * 3072 + h * 64 + d] * (1.0f / 4096.0f);
  __syncthreads();
  if (d < 32){
    float z = b1[d];
    for (int j = 0; j < 64; j++) z = fmaf(qm[j], W1[d * 64 + j], z);
    h1s[d] = z / (1.0f + __expf(-z));             // silu
  }
  __syncthreads();
  if (d == 0){
    float z2 = b2[0];
    for (int j = 0; j < 32; j++) z2 = fmaf(h1s[j], W2[j], z2);
    out_pulse[b * H_ + h] = 4.0f + log1pf(__expf(z2));  // PULSE_BASE+softplus
  }
  if (d < 32){
    const int k = d;
    const float* qrow = qkvC + (size_t)(b * K_ + k) * 3072 + h * 64;
    const float* krow = qrow + 1024;
    float s = 0.f;
    for (int j = 0; j < 64; j++) s = fmaf(qrow[j], krow[j], s);
    float fg = 1.0f / (1.0f + __expf(-filt[h * 32 + k]));
    s = s * 0.125f * fg;                          // /sqrt(64)*sigmoid(filter)
    float av = a_in[0], bv = b_in[0];
    float sc = fmaxf(fabsf(s), 1e-6f);
    float sn = s / sc;
    float I  = (fabsf(s) > 0.5f) ? sn : 0.1f * sn;
    float v = 0.f, w = 0.f;
    #pragma unroll
    for (int it = 0; it < 5; ++it){
      float dv = v - v * v * v * (1.0f / 3.0f) - w + I;
      float dw = (v + av - bv * w) * 10.0f;       // /TAU
      v = fminf(fmaxf(v + 0.2f * dv, -3.0f), 3.0f);
      w = fminf(fmaxf(w + 0.2f * dw, -3.0f), 3.0f);
    }
    float r = v * sc;
    rsp[k] = r;
    out_resp[(b * H_ + h) * K_ + k] = r;
  }
  __syncthreads();
  for (int k = 0; k < 32; k++){
    u[(size_t)(b * K_ + k) * D_ + h * 64 + d] =
        rsp[k] * qkvC[(size_t)(b * K_ + k) * 3072 + 2048 + h * 64 + d];
  }
}

// ---------------------------------------------------------------------------
// k4_main: out0 rows [row_begin, row_begin + 32*gridDim.y), f32 stores.
// grid (2, nchunks), block 256; thread owns 2 consecutive e; 32 rows/chunk.
// Chunks never cross a b boundary and never touch rows [896,1024).
// ---------------------------------------------------------------------------
__global__ __launch_bounds__(256) void k4_main(
    const float* __restrict__ sb, const float* __restrict__ Mf,
    float* __restrict__ out, const int row_begin)
{
  const int r0 = row_begin + blockIdx.y * 32;
  const int b  = r0 >> 12;
  const int e0 = blockIdx.x * 512 + threadIdx.x * 2;
  __shared__ float sbs[32][33];
  #pragma unroll
  for (int i = 0; i < 4; i++){
    int idx = threadIdx.x + i * 256;           // 1024 = 32t * 32k
    int k = idx & 31, t = idx >> 5;
    sbs[t][k] = sb[(size_t)(r0 + t) * K_ + k];
  }
  __syncthreads();
  float mx[32], my[32];
  const float* mp = Mf + (size_t)b * K_ * D_ + e0;
  #pragma unroll
  for (int k = 0; k < 32; k++){ mx[k] = mp[(size_t)k * D_]; my[k] = mp[(size_t)k * D_ + 1]; }
  float* op = out + (size_t)r0 * D_ + e0;
  for (int t = 0; t < 32; ++t){
    float ox = 0.f, oy = 0.f;
    #pragma unroll
    for (int k = 0; k < 32; k++){
      float s = sbs[t][k];
      ox = fmaf(s, mx[k], ox);
      oy = fmaf(s, my[k], oy);
    }
    float2 o2; o2.x = ox; o2.y = oy;
    *(float2*)(op + (size_t)t * D_) = o2;
  }
}

// ---------------------------------------------------------------------------
// k4_tail: out0 rows [896,1024) — M's home. ONE block preloads M[b=0]
// (128 KB) into LDS, syncs, then overwrites. Intra-block => race-free.
// LDS: 131072 + 16896 = 147968 B < 160 KB.
// ---------------------------------------------------------------------------
__global__ __launch_bounds__(256) void k4_tail(
    const float* __restrict__ sb, const float* __restrict__ Mf,
    float* __restrict__ out)
{
  __shared__ float Ml[32][1024];               // 128 KB
  __shared__ float sbs[128][33];
  #pragma unroll
  for (int i = 0; i < 128; i++){
    int idx = threadIdx.x + i * 256;           // 32768 = M[b=0]
    Ml[idx >> 10][idx & 1023] = Mf[idx];
  }
  #pragma unroll
  for (int i = 0; i < 16; i++){
    int idx = threadIdx.x + i * 256;           // 4096 = 128t * 32k
    int k = idx & 31, t = idx >> 5;
    sbs[t][k] = sb[(size_t)(896 + t) * K_ + k];
  }
  __syncthreads();
  const int e0 = threadIdx.x * 4;              // each thread owns 4 e
  float* op = out + (size_t)896 * D_ + e0;
  for (int t = 0; t < 128; ++t){
    float o0 = 0.f, o1 = 0.f, o2 = 0.f, o3 = 0.f;
    #pragma unroll
    for (int k = 0; k < 32; k++){
      float s = sbs[t][k];
      o0 = fmaf(s, Ml[k][e0],     o0);
      o1 = fmaf(s, Ml[k][e0 + 1], o1);
      o2 = fmaf(s, Ml[k][e0 + 2], o2);
      o3 = fmaf(s, Ml[k][e0 + 3], o3);
    }
    float4 o4; o4.x = o0; o4.y = o1; o4.z = o2; o4.w = o3;
    *(float4*)(op + (size_t)t * D_) = o4;
  }
}

// ---------------------------------------------------------------------------
extern "C" void kernel_launch(void* const* d_in, const int* in_sizes, int n_in,
                              void* d_out, int out_size, void* d_ws, size_t ws_size,
                              hipStream_t stream)
{
  const float* x    = (const float*)d_in[0];
  const float* sb   = (const float*)d_in[1];
  const float* Wqkv = (const float*)d_in[2];
  const float* Wout = (const float*)d_in[3];
  const float* a_in = (const float*)d_in[4];
  const float* b_in = (const float*)d_in[5];
  const float* W1   = (const float*)d_in[6];
  const float* b1   = (const float*)d_in[7];
  const float* W2   = (const float*)d_in[8];
  const float* b2   = (const float*)d_in[9];
  const float* filt = (const float*)d_in[10];

  float* outF = (float*)d_out;
  float* xs   = outF;                 // see layout comment above
  float* xbar = outF + 131072;
  float* qkv  = outF + 196608;
  float* u    = outF + 786432;
  float* Mm   = outF + 917504;        // f32 M, out0 rows [896,1024)
  float* pulse = outF + 16777216;     // (B,H)   f32
  float* resp  = outF + 16777280;     // (B,H,K) f32

  k0_init<<<dim3(768), 256, 0, stream>>>((float4*)outF, 196608,
                                         (float4*)Mm, 32768);
  k1_spectral<<<dim3(2, 4, 32), 256, 0, stream>>>(x, sb, xs, xbar);
  gemm_aw<<<dim3(48, 3, 4), 256, 0, stream>>>(outF, Wqkv, qkv, 3072, 256);
  k3_small<<<dim3(64), dim3(64), 0, stream>>>(qkv, W1, b1, W2, b2,
                                              filt, a_in, b_in, u,
                                              pulse, resp);
  gemm_aw<<<dim3(16, 2, 8), 256, 0, stream>>>(u, Wout, Mm, 1024, 128);
  // Phase A: all out0 rows except M's home [896,1024)
  k4_main<<<dim3(2, 28), 256, 0, stream>>>(sb, Mm, outF, 0);      // rows [0,896)
  k4_main<<<dim3(2, 480), 256, 0, stream>>>(sb, Mm, outF, 1024);  // rows [1024,16384)
  // Phase B: rows [896,1024), one block, LDS-preloaded M[b=0]
  k4_tail<<<dim3(1), 256, 0, stream>>>(sb, Mm, outF);
}